// Round 1
// 1995.173 us; speedup vs baseline: 1.0223x; 1.0223x over previous
//
#include <hip/hip_runtime.h>
#include <hip/hip_fp16.h>

typedef unsigned int  u32;
typedef unsigned short u16;
typedef _Float16 half_t;
typedef _Float16 f16x8 __attribute__((ext_vector_type(8)));
typedef _Float16 h2    __attribute__((ext_vector_type(2)));
typedef float    f32x4 __attribute__((ext_vector_type(4)));

#define B_   64
#define T_   512
#define NUMC 2000
#define H_   256
#define ATT  80
#define D_   352
#define BT_  32768   // B*T
#define G4   1024    // 4*H

// ---------------- helpers ----------------
__device__ __forceinline__ float fdot2f(u32 a, u32 b, float c) {
#if __has_builtin(__builtin_amdgcn_fdot2)
  return __builtin_amdgcn_fdot2(__builtin_bit_cast(h2, a), __builtin_bit_cast(h2, b), c, false);
#else
  h2 ha = __builtin_bit_cast(h2, a), hb = __builtin_bit_cast(h2, b);
  return c + (float)ha.x * (float)hb.x + (float)ha.y * (float)hb.y;
#endif
}

__device__ __forceinline__ void load_lds16(const void* g, void* l) {
  __builtin_amdgcn_global_load_lds((const __attribute__((address_space(1))) void*)g,
                                   (__attribute__((address_space(3))) void*)l, 16, 0, 0);
}

__device__ __forceinline__ u32 pack2f(float x, float y) {
  h2 h; h.x = (_Float16)x; h.y = (_Float16)y;
  return __builtin_bit_cast(u32, h);
}

__device__ __forceinline__ float sigmoidf_(float x) { return 1.f / (1.f + __expf(-x)); }

// fast tanh: 1 - 2/(e^{2x}+1). Saturates correctly for |x| large; ~1e-7 err.
// Replaces branchy ocml tanhf on the serial per-timestep critical path.
__device__ __forceinline__ float fast_tanhf(float x) {
  float e = __expf(2.f * x);
  return 1.f - 2.f / (e + 1.f);
}

__device__ __forceinline__ int  sel4i(int4 v, int q) { return q==0?v.x:q==1?v.y:q==2?v.z:v.w; }
__device__ __forceinline__ u32  sel4u(uint4 v, int q){ return q==0?v.x:q==1?v.y:q==2?v.z:v.w; }

// ---------------- weight prep: f32 -> f16 (+ zero padding) ----------------
__global__ void prep_weights(const float* __restrict__ Wih, const float* __restrict__ mlp_w,
                             const float* __restrict__ fc_w,
                             half_t* __restrict__ wih_h, half_t* __restrict__ mlp_p,
                             half_t* __restrict__ fc_p)
{
  int i = blockIdx.x * 256 + threadIdx.x;
  if (i < 360448) { wih_h[i] = (half_t)Wih[i]; return; }
  i -= 360448;
  if (i < 32768) {          // [128][256], rows>=80 zero
    int row = i >> 8;
    mlp_p[i] = (row < ATT) ? (half_t)mlp_w[i] : (half_t)0.f;
    return;
  }
  i -= 32768;
  if (i < 1048576) {        // [2048][512], rows>=2000 zero
    int row = i >> 9;
    fc_p[i] = (row < NUMC) ? (half_t)fc_w[i] : (half_t)0.f;
  }
}

// ---------------- gather sae (output #2) + f16 copy for GEMM ----------------
// one block per token, 128 threads, d = tid + k*128 (no div/mod)
__global__ __launch_bounds__(128)
void gather_sae(const int* __restrict__ skill, const int* __restrict__ answer,
                const float* __restrict__ semb, const float* __restrict__ aemb,
                float* __restrict__ sae, half_t* __restrict__ sae_h)
{
  const int tok = blockIdx.x;
  const int tid = threadIdx.x;
  const int s = skill[tok], a = answer[tok];
  float* so = sae + (size_t)tok * D_;
  half_t* ho = sae_h + (size_t)tok * D_;
#pragma unroll
  for (int k = 0; k < 3; ++k) {
    int d = tid + k * 128;
    if (d >= D_) break;
    float v;
    if (a == 1) v = (d < 256) ? semb[s * 256 + d]  : aemb[96 + (d - 256)];
    else        v = (d < 96)  ? aemb[a * 96 + d]   : semb[s * 256 + (d - 96)];
    so[d] = v;
    ho[d] = (half_t)v;
  }
}

// ---------------- f16 MFMA GEMM, out = A[M,K] @ B[N,K]^T, 128x128 tile, BK=32 ----
template<int EPI>
__global__ __launch_bounds__(256)
void gemm_bt(const half_t* __restrict__ A, const half_t* __restrict__ Bm,
             float* __restrict__ Cf, half_t* __restrict__ Ch,
             const float* __restrict__ b0, const float* __restrict__ b1,
             int K, int N, int Nout)
{
  __shared__ half_t At [128 * 32];
  __shared__ half_t Bt2[128 * 32];
  const int tid  = threadIdx.x;
  const int lane = tid & 63;
  const int wv   = tid >> 6;
  const int m0   = blockIdx.x * 128;
  const int n0   = blockIdx.y * 128;
  const int wm   = (wv & 1) * 64, wn = (wv >> 1) * 64;
  const int lrow = wv * 16 + (lane >> 2);
  const int lk   = (lane & 3) * 8;

  f32x4 acc[4][4];
#pragma unroll
  for (int mi = 0; mi < 4; ++mi)
#pragma unroll
    for (int ni = 0; ni < 4; ++ni) acc[mi][ni] = (f32x4){0.f, 0.f, 0.f, 0.f};

  for (int k0 = 0; k0 < K; k0 += 32) {
    load_lds16(A  + (size_t)(m0 + lrow)      * K + k0 + lk, &At [wv * 512]);
    load_lds16(A  + (size_t)(m0 + 64 + lrow) * K + k0 + lk, &At [2048 + wv * 512]);
    load_lds16(Bm + (size_t)(n0 + lrow)      * K + k0 + lk, &Bt2[wv * 512]);
    load_lds16(Bm + (size_t)(n0 + 64 + lrow) * K + k0 + lk, &Bt2[2048 + wv * 512]);
    __syncthreads();
    f16x8 af[4], bf[4];
#pragma unroll
    for (int mi = 0; mi < 4; ++mi)
      af[mi] = *(const f16x8*)&At [(wm + mi * 16 + (lane & 15)) * 32 + (lane >> 4) * 8];
#pragma unroll
    for (int ni = 0; ni < 4; ++ni)
      bf[ni] = *(const f16x8*)&Bt2[(wn + ni * 16 + (lane & 15)) * 32 + (lane >> 4) * 8];
    __syncthreads();
#pragma unroll
    for (int mi = 0; mi < 4; ++mi)
#pragma unroll
      for (int ni = 0; ni < 4; ++ni)
        acc[mi][ni] = __builtin_amdgcn_mfma_f32_16x16x32_f16(af[mi], bf[ni], acc[mi][ni], 0, 0, 0);
  }

  const int rbase = (lane >> 4) * 4;
  const int cidx  = lane & 15;
#pragma unroll
  for (int mi = 0; mi < 4; ++mi) {
#pragma unroll
    for (int ni = 0; ni < 4; ++ni) {
      int gc = n0 + wn + ni * 16 + cidx;
#pragma unroll
      for (int r = 0; r < 4; ++r) {
        int gr = m0 + wm + mi * 16 + rbase + r;
        float v = acc[mi][ni][r];
        if (EPI == 0) {
          Ch[(size_t)gr * N + gc] = (half_t)(v + b0[gc] + b1[gc]);
        } else if (EPI == 1) {
          Cf[(size_t)gr * N + gc] = v;
        } else {
          if (gc < Nout) Cf[(size_t)gr * Nout + gc] = sigmoidf_(v + b0[gc]);
        }
      }
    }
  }
}

// ---------------- LSTM: 1 block / batch, 512 threads, thread owns gate rows tid, tid+512
// Whh f16 pairs: 96 pairs/gate-row in VGPRs (192 regs), 32 pairs/row in LDS (128 KB).
// VGPR budget MUST be 256 (2 waves/EU = exactly one 512-thread block per CU).
// amdgpu_waves_per_eu(2,2) did NOT take effect (rocprof showed VGPR_Count=128,
// both weight arrays spilled to scratch, 1257 us @ VALUBusy 14.5%).
// __launch_bounds__(512, 2): 2nd arg = min waves per EU -> VGPR cap 512/2 = 256.
#define RPV 96
__global__ __launch_bounds__(512, 2)
void lstm_kernel(const half_t* __restrict__ xg, const float* __restrict__ Whh,
                 u32* __restrict__ hout /* [32768][128] f16-pairs */)
{
  __shared__ uint4 wlds[8 * 1024];                 // pair groups g: pairs 96+4g..96+4g+3
  __shared__ float gbuf[1024];
  __shared__ __align__(16) u16 hq[256];            // h as f16
  const int tid  = threadIdx.x;
  const int lane = tid & 63;
  const int b    = blockIdx.x;
  const int j0   = tid, j1 = tid + 512;

  u32 wA[RPV], wB[RPV];
#pragma unroll
  for (int p = 0; p < RPV; ++p) {
    float2 a = *(const float2*)&Whh[j0 * 256 + 2 * p];
    float2 c = *(const float2*)&Whh[j1 * 256 + 2 * p];
    wA[p] = pack2f(a.x, a.y);
    wB[p] = pack2f(c.x, c.y);
  }
#pragma unroll
  for (int g = 0; g < 8; ++g) {
    const float* pa = &Whh[j0 * 256 + 2 * (RPV + 4 * g)];
    const float* pb = &Whh[j1 * 256 + 2 * (RPV + 4 * g)];
    uint4 wa, wb;
    wa.x = pack2f(pa[0], pa[1]); wa.y = pack2f(pa[2], pa[3]);
    wa.z = pack2f(pa[4], pa[5]); wa.w = pack2f(pa[6], pa[7]);
    wb.x = pack2f(pb[0], pb[1]); wb.y = pack2f(pb[2], pb[3]);
    wb.z = pack2f(pb[4], pb[5]); wb.w = pack2f(pb[6], pb[7]);
    wlds[g * 1024 + j0] = wa;
    wlds[g * 1024 + j1] = wb;
  }
  if (tid < 128) ((u32*)hq)[tid] = 0u;
  float cst = 0.f;
  const half_t* xrow = xg + (size_t)b * T_ * G4;
  float x0 = (float)xrow[j0], x1 = (float)xrow[j1];
  __syncthreads();

  for (int t = 0; t < T_; ++t) {
    int4 hv = ((const int4*)hq)[lane & 31];        // pairs 4L..4L+3 in lane L (L<32)
    float acc0 = x0, acc1 = x1;
    if (t < T_ - 1) {                              // prefetch next xt
      x0 = (float)xrow[(size_t)(t + 1) * G4 + j0];
      x1 = (float)xrow[(size_t)(t + 1) * G4 + j1];
    }
#pragma unroll
    for (int p = 0; p < RPV; ++p) {
      u32 hp = (u32)__builtin_amdgcn_readlane(sel4i(hv, p & 3), p >> 2);
      acc0 = fdot2f(hp, wA[p], acc0);
      acc1 = fdot2f(hp, wB[p], acc1);
    }
#pragma unroll
    for (int g = 0; g < 8; ++g) {
      uint4 wa = wlds[g * 1024 + j0];
      uint4 wb = wlds[g * 1024 + j1];
#pragma unroll
      for (int q = 0; q < 4; ++q) {
        int p = RPV + 4 * g + q;
        u32 hp = (u32)__builtin_amdgcn_readlane(sel4i(hv, p & 3), p >> 2);
        acc0 = fdot2f(hp, sel4u(wa, q), acc0);
        acc1 = fdot2f(hp, sel4u(wb, q), acc1);
      }
    }
    gbuf[j0] = acc0;
    gbuf[j1] = acc1;
    __syncthreads();
    if (tid < 256) {                               // gates (i,f,g,o) of h-index tid
      float gi = gbuf[tid], gf = gbuf[tid + 256], gg = gbuf[tid + 512], go = gbuf[tid + 768];
      cst = sigmoidf_(gf) * cst + sigmoidf_(gi) * fast_tanhf(gg);
      float h = sigmoidf_(go) * fast_tanhf(cst);
      hq[tid] = __builtin_bit_cast(u16, (_Float16)h);
    }
    __syncthreads();
    if (tid < 128) hout[(size_t)(b * T_ + t) * 128 + tid] = ((const u32*)hq)[tid];
  }
}

// ---------------- attention: scores, softmax-cumsum, build final=[cum1|h] f16 ----
__global__ __launch_bounds__(256)
void attn_kernel(const float* __restrict__ sp /*[32768][128]*/, const float* __restrict__ mlp_b,
                 const float* __restrict__ sim_w, const half_t* __restrict__ hh /*[32768][256]*/,
                 half_t* __restrict__ fin /*[32768][512]*/)
{
  __shared__ float e[T_];
  __shared__ float red[4];
  const int tid = threadIdx.x;
  const int b   = blockIdx.x;

  float sc0 = 0.f, sc1 = 0.f;
  {
    const float* r0 = sp + (size_t)(b * T_ + tid) * 128;
    const float* r1 = sp + (size_t)(b * T_ + tid + 256) * 128;
    for (int a = 0; a < ATT; ++a) {
      float w = sim_w[a], bb = mlp_b[a];
      sc0 += fast_tanhf(r0[a] + bb) * w;
      sc1 += fast_tanhf(r1[a] + bb) * w;
    }
  }
  float smax = fmaxf(sc0, sc1);
#pragma unroll
  for (int off = 1; off < 64; off <<= 1) smax = fmaxf(smax, __shfl_xor(smax, off, 64));
  if ((tid & 63) == 0) red[tid >> 6] = smax;
  __syncthreads();
  float m = fmaxf(fmaxf(red[0], red[1]), fmaxf(red[2], red[3]));
  e[tid]       = __expf(sc0 - m);
  e[tid + 256] = __expf(sc1 - m);
  __syncthreads();

  float num = 0.f, den = 0.f, c1 = 0.f;
  const half_t* hbase = hh + (size_t)b * T_ * H_ + tid;   // thread = hidden index
  half_t* fbase = fin + (size_t)b * T_ * 512;
  float pre[4];
#pragma unroll
  for (int d = 0; d < 4; ++d) pre[d] = (float)hbase[(size_t)d * H_];
  for (int t = 0; t < T_; ++t) {
    float hv = pre[t & 3];
    if (t + 4 < T_) pre[t & 3] = (float)hbase[(size_t)(t + 4) * H_];
    float et = e[t];
    den += et;
    num += et * hv;
    float attn = num / den;
    half_t* fr = fbase + (size_t)t * 512;
    fr[tid]       = (half_t)c1;     // exclusive cumsum of attn
    fr[256 + tid] = (half_t)hv;
    c1 += attn;
  }
}

// ---------------- launch ----------------
extern "C" void kernel_launch(void* const* d_in, const int* in_sizes, int n_in,
                              void* d_out, int out_size, void* d_ws, size_t ws_size,
                              hipStream_t stream)
{
  (void)in_sizes; (void)n_in; (void)out_size; (void)ws_size;
  const int*   skill  = (const int*)d_in[0];
  const int*   answer = (const int*)d_in[1];
  const float* semb   = (const float*)d_in[2];
  const float* aemb   = (const float*)d_in[3];
  const float* Wih    = (const float*)d_in[4];
  const float* Whh    = (const float*)d_in[5];
  const float* bih    = (const float*)d_in[6];
  const float* bhh    = (const float*)d_in[7];
  const float* mlp_w  = (const float*)d_in[8];
  const float* mlp_b  = (const float*)d_in[9];
  const float* sim_w  = (const float*)d_in[10];
  const float* fc_w   = (const float*)d_in[11];
  const float* fc_b   = (const float*)d_in[12];

  float* res = (float*)d_out;                          // [32768][2000]
  float* sae = (float*)d_out + (size_t)BT_ * NUMC;     // [32768][352]

  // Workspace (~127 MB). fin aliases xg_h: xg dead after lstm_kernel.
  char* ws = (char*)d_ws;
  half_t* sae_h = (half_t*)(ws + 0);                   // 23,068,672 B
  half_t* wih_h = (half_t*)(ws + 23068672);            //    720,896 B
  half_t* mlp_p = (half_t*)(ws + 23789568);            //     65,536 B
  half_t* fc_p  = (half_t*)(ws + 23855104);            //  2,097,152 B
  half_t* xg_h  = (half_t*)(ws + 25952256);            // 67,108,864 B
  half_t* fin   = (half_t*)(ws + 25952256);            // 33,554,432 B (aliases xg_h)
  u32*    h2u   = (u32*)   (ws + 93061120);            // 16,777,216 B
  float*  sp    = (float*) (ws + 109838336);           // 16,777,216 B

  prep_weights<<<5632, 256, 0, stream>>>(Wih, mlp_w, fc_w, wih_h, mlp_p, fc_p);
  gather_sae<<<BT_, 128, 0, stream>>>(skill, answer, semb, aemb, sae, sae_h);
  gemm_bt<0><<<dim3(256, 8), 256, 0, stream>>>(sae_h, wih_h, nullptr, xg_h, bih, bhh, 352, 1024, 0);
  lstm_kernel<<<64, 512, 0, stream>>>(xg_h, Whh, h2u);
  gemm_bt<1><<<dim3(256, 1), 256, 0, stream>>>((const half_t*)h2u, mlp_p, sp, nullptr, nullptr, nullptr, 256, 128, 0);
  attn_kernel<<<64, 256, 0, stream>>>(sp, mlp_b, sim_w, (const half_t*)h2u, fin);
  gemm_bt<2><<<dim3(256, 16), 256, 0, stream>>>(fin, fc_p, res, nullptr, fc_b, nullptr, 512, 2048, NUMC);
}